// Round 6
// baseline (1524.810 us; speedup 1.0000x reference)
//
#include <hip/hip_runtime.h>

#define HIDDEN  64
#define T_LEN   4096
#define CHUNK   32
#define MLP_HID 40
#define HP      68      // h_hist row pitch (floats)
#define W1P     68
#define ZP      41

typedef float v2f __attribute__((ext_vector_type(2)));
typedef float v4f __attribute__((ext_vector_type(4)));

#define LO2(x) __builtin_shufflevector(x, x, 0, 1)
#define HI2(x) __builtin_shufflevector(x, x, 2, 3)

// ---- VOP3P packed fp32 with op_sel broadcast (no cross-lane: hazard-safe) ----
// lo variant: both output halves use src0.LO (h_even broadcast)
__device__ __forceinline__ v2f pk_mul_lo(v2f h, v2f w) {
    v2f d;
    asm("v_pk_mul_f32 %0, %1, %2 op_sel:[0,0] op_sel_hi:[0,1]"
        : "=v"(d) : "v"(h), "v"(w));
    return d;
}
// hi variant: both output halves use src0.HI (h_odd broadcast)
__device__ __forceinline__ v2f pk_mul_hi(v2f h, v2f w) {
    v2f d;
    asm("v_pk_mul_f32 %0, %1, %2 op_sel:[1,0] op_sel_hi:[1,1]"
        : "=v"(d) : "v"(h), "v"(w));
    return d;
}
__device__ __forceinline__ v2f pk_fma_lo(v2f h, v2f w, v2f c) {
    v2f d;
    asm("v_pk_fma_f32 %0, %1, %2, %3 op_sel:[0,0,0] op_sel_hi:[0,1,1]"
        : "=v"(d) : "v"(h), "v"(w), "v"(c));
    return d;
}
__device__ __forceinline__ v2f pk_fma_hi(v2f h, v2f w, v2f c) {
    v2f d;
    asm("v_pk_fma_f32 %0, %1, %2, %3 op_sel:[1,0,0] op_sel_hi:[1,1,1]"
        : "=v"(d) : "v"(h), "v"(w), "v"(c));
    return d;
}
__device__ __forceinline__ v2f pk_add(v2f a, v2f b) {
    v2f d;
    asm("v_pk_add_f32 %0, %1, %2" : "=v"(d) : "v"(a), "v"(b));
    return d;
}

// cross-lane via builtins ONLY (compiler inserts DPP hazard wait-states;
// raw v_add_f32_dpp asm caused a numerics failure in round 3)
__device__ __forceinline__ float dpp_x1(float v) {   // quad_perm [1,0,3,2]
    return __int_as_float(__builtin_amdgcn_update_dpp(
        0, __float_as_int(v), 0xB1, 0xF, 0xF, true));
}
__device__ __forceinline__ float dpp_x2(float v) {   // quad_perm [2,3,0,1]
    return __int_as_float(__builtin_amdgcn_update_dpp(
        0, __float_as_int(v), 0x4E, 0xF, 0xF, true));
}
__device__ __forceinline__ float fast_sigmoid(float x) {
    float e = __builtin_amdgcn_exp2f(x * -1.4426950408889634f);
    return __builtin_amdgcn_rcpf(1.0f + e);
}

__global__ __launch_bounds__(256, 1)
void lstm_mlp_kernel(const float* __restrict__ inputs,
                     const float* __restrict__ W_ih,
                     const float* __restrict__ W_hh,
                     const float* __restrict__ b_ih,
                     const float* __restrict__ b_hh,
                     const float* __restrict__ W1,
                     const float* __restrict__ b1,
                     const float* __restrict__ W2,
                     const float* __restrict__ b2,
                     float* __restrict__ out)
{
    __shared__ __align__(16) float x_lds[T_LEN];
    __shared__ __align__(16) float h_hist[CHUNK * HP];
    __shared__ __align__(16) float w1_lds[MLP_HID * W1P];
    __shared__ float b1_lds[MLP_HID];
    __shared__ float w2_lds[MLP_HID];
    __shared__ float z_lds[CHUNK * ZP];

    const int tid = threadIdx.x;
    const int b   = blockIdx.x;
    const int w   = tid >> 6;
    const int l   = tid & 63;
    const int r   = l >> 2;
    const int q   = l & 3;           // quad role: gate type AND K-chunk
    const int u   = 16 * w + r;      // hidden unit owned by this quad
    const bool q1 = (q & 1) != 0;
    const bool q2 = (q & 2) != 0;
    const bool wlane = (q == 1);

    // ---- prologue ----
    const float4* in4 = (const float4*)(inputs + (size_t)b * T_LEN);
    float4* x4 = (float4*)x_lds;
    #pragma unroll
    for (int rr = 0; rr < 4; ++rr) x4[tid + 256 * rr] = in4[tid + 256 * rr];

    // W_hh rows for gates i,f,g,o of unit u, slice [16q,16q+16), repacked as
    // {i,f} and {g,o} pairs for op_sel-broadcast pk_fma.
    v2f wIF[16], wGO[16];
    {
        v4f rows[4][4];
        #pragma unroll
        for (int j = 0; j < 4; ++j) {
            const v4f* p = (const v4f*)(W_hh + (j * 64 + u) * HIDDEN + 16 * q);
            #pragma unroll
            for (int m = 0; m < 4; ++m) rows[j][m] = p[m];
        }
        #pragma unroll
        for (int m = 0; m < 4; ++m) {
            #pragma unroll
            for (int e = 0; e < 4; ++e) {
                wIF[4 * m + e] = (v2f){rows[0][m][e], rows[1][m][e]};
                wGO[4 * m + e] = (v2f){rows[2][m][e], rows[3][m][e]};
            }
        }
    }
    // own gate (type q, unit u) — round-2 exact numerics
    const int   gown = q * 64 + u;
    const float wq   = W_ih[gown];
    const float bq   = b_ih[gown] + b_hh[gown];
    const float m_c  = (q == 2) ?  2.8853900817779268f : -1.4426950408889634f;
    const float a_c  = (q == 2) ? -2.0f : 1.0f;
    const float d_c  = (q == 2) ?  1.0f : 0.0f;
    const float b2v  = b2[0];

    for (int p = tid; p < MLP_HID * 65; p += 256) {
        int row = p / 65, col = p - row * 65;
        w1_lds[row * W1P + col] = W1[p];
    }
    if (tid < MLP_HID) { b1_lds[tid] = b1[tid]; w2_lds[tid] = W2[tid]; }
    if (tid < HIDDEN)  h_hist[31 * HP + tid] = 0.0f;   // h(-1) in row 31
    float c = 0.0f;
    __syncthreads();

    float* outb = out + (size_t)b * T_LEN;
    const float* hq_base = h_hist + 16 * q;   // this lane's K-slice base
    float*       hwp     = h_hist + u;        // this lane's write column

    for (int tc = 0; tc < T_LEN / CHUNK; ++tc) {
        const float* xcb = x_lds + tc * CHUNK;

        #pragma unroll
        for (int tt = 0; tt < CHUNK; ++tt) {
            const int rp = (tt + CHUNK - 1) & (CHUNK - 1);  // compile-time row
            const v4f* h4 = (const v4f*)(hq_base + rp * HP);
            v4f ha = h4[0], hb = h4[1], hc = h4[2], hd = h4[3];
            float xv = xcb[tt];

            // ---- matvec: 4 gates x 16 K as op_sel-broadcast pk ops ----
            v2f pa = LO2(ha), pb = HI2(ha);
            v2f aIF0 = pk_mul_lo(pa, wIF[0]);
            v2f aIF1 = pk_mul_hi(pa, wIF[1]);
            v2f aGO0 = pk_mul_lo(pa, wGO[0]);
            v2f aGO1 = pk_mul_hi(pa, wGO[1]);
            aIF0 = pk_fma_lo(pb, wIF[2], aIF0);
            aIF1 = pk_fma_hi(pb, wIF[3], aIF1);
            aGO0 = pk_fma_lo(pb, wGO[2], aGO0);
            aGO1 = pk_fma_hi(pb, wGO[3], aGO1);

            pa = LO2(hb); pb = HI2(hb);
            aIF0 = pk_fma_lo(pa, wIF[4], aIF0);
            aIF1 = pk_fma_hi(pa, wIF[5], aIF1);
            aGO0 = pk_fma_lo(pa, wGO[4], aGO0);
            aGO1 = pk_fma_hi(pa, wGO[5], aGO1);
            aIF0 = pk_fma_lo(pb, wIF[6], aIF0);
            aIF1 = pk_fma_hi(pb, wIF[7], aIF1);
            aGO0 = pk_fma_lo(pb, wGO[6], aGO0);
            aGO1 = pk_fma_hi(pb, wGO[7], aGO1);

            pa = LO2(hc); pb = HI2(hc);
            aIF0 = pk_fma_lo(pa, wIF[8], aIF0);
            aIF1 = pk_fma_hi(pa, wIF[9], aIF1);
            aGO0 = pk_fma_lo(pa, wGO[8], aGO0);
            aGO1 = pk_fma_hi(pa, wGO[9], aGO1);
            aIF0 = pk_fma_lo(pb, wIF[10], aIF0);
            aIF1 = pk_fma_hi(pb, wIF[11], aIF1);
            aGO0 = pk_fma_lo(pb, wGO[10], aGO0);
            aGO1 = pk_fma_hi(pb, wGO[11], aGO1);

            pa = LO2(hd); pb = HI2(hd);
            aIF0 = pk_fma_lo(pa, wIF[12], aIF0);
            aIF1 = pk_fma_hi(pa, wIF[13], aIF1);
            aGO0 = pk_fma_lo(pa, wGO[12], aGO0);
            aGO1 = pk_fma_hi(pa, wGO[13], aGO1);
            aIF0 = pk_fma_lo(pb, wIF[14], aIF0);
            aIF1 = pk_fma_hi(pb, wIF[15], aIF1);
            aGO0 = pk_fma_lo(pb, wGO[14], aGO0);
            aGO1 = pk_fma_hi(pb, wGO[15], aGO1);

            v2f accIF = pk_add(aIF0, aIF1);
            v2f accGO = pk_add(aGO0, aGO1);
            float acc0 = accIF.x, acc1 = accIF.y;   // i, f slice-sums
            float acc2 = accGO.x, acc3 = accGO.y;   // g, o slice-sums

            // butterfly stage 1 (builtin DPP), per-lane select, stage 2
            acc0 += dpp_x1(acc0);
            acc1 += dpp_x1(acc1);
            acc2 += dpp_x1(acc2);
            acc3 += dpp_x1(acc3);
            float t0 = q1 ? acc1 : acc0;
            float t1 = q1 ? acc3 : acc2;
            float s_own  = q2 ? t1 : t0;
            float s_part = q2 ? t0 : t1;
            float tot = s_own + dpp_x2(s_part);    // full own-gate sum

            // single activation per lane (round-2 exact form)
            float pre = tot + fmaf(xv, wq, bq);
            float act = fmaf(a_c, __builtin_amdgcn_rcpf(
                              1.0f + __builtin_amdgcn_exp2f(m_c * pre)), d_c);

            // quad exchange: f and i*g to all lanes (lane q==1 keeps o)
            float recv = dpp_x2(act);              // 0:g 1:o 2:i 3:f
            float p    = act * recv;               // lanes 0,2: i*g
            float e0 = q2 ? recv : act;
            float e  = q1 ? e0 : p;
            float rr = dpp_x1(e);
            float fv = q1 ? e : rr;
            float ig = q1 ? rr : e;
            c = fmaf(fv, c, ig);
            float th = fmaf(-2.0f, __builtin_amdgcn_rcpf(
                             1.0f + __builtin_amdgcn_exp2f(2.8853900817779268f * c)), 1.0f);
            float ov = q2 ? act : recv;            // o (valid on lane q==1)
            float hn = ov * th;
            if (wlane) hwp[tt * HP] = hn;
            __syncthreads();
        }

        // ---- fused MLP head for this chunk ----
        {
            int tbase = tc * CHUNK;
            int tl = tid >> 3, j0 = tid & 7;
            float4 hh[16];
            const float4* hr = (const float4*)(h_hist + tl * HP);
            #pragma unroll
            for (int m = 0; m < 16; ++m) hh[m] = hr[m];
            float xc = x_lds[tbase + tl];
            #pragma unroll
            for (int jj = 0; jj < 5; ++jj) {
                int j = j0 + 8 * jj;
                const float4* w1r = (const float4*)(w1_lds + j * W1P);
                float a0 = b1_lds[j], a1 = 0.f, a2 = 0.f, a3 = 0.f;
                #pragma unroll
                for (int m = 0; m < 16; ++m) {
                    float4 wv = w1r[m];
                    a0 = fmaf(hh[m].x, wv.x, a0);
                    a1 = fmaf(hh[m].y, wv.y, a1);
                    a2 = fmaf(hh[m].z, wv.z, a2);
                    a3 = fmaf(hh[m].w, wv.w, a3);
                }
                float zacc = ((a0 + a1) + (a2 + a3)) + xc * w1_lds[j * W1P + 64];
                z_lds[tl * ZP + j] = fast_sigmoid(zacc);
            }
            __syncthreads();
            if (tid < CHUNK) {
                float y = b2v;
                #pragma unroll
                for (int j = 0; j < MLP_HID; ++j)
                    y = fmaf(w2_lds[j], z_lds[tid * ZP + j], y);
                outb[tbase + tid] = y;
            }
            // next h_hist write (row 0) is fenced by the mid-MLP barrier;
            // hh/z values are already consumed — no trailing barrier needed.
        }
    }
}

extern "C" void kernel_launch(void* const* d_in, const int* in_sizes, int n_in,
                              void* d_out, int out_size, void* d_ws, size_t ws_size,
                              hipStream_t stream) {
    const float* inputs = (const float*)d_in[0];
    const float* W_ih   = (const float*)d_in[1];
    const float* W_hh   = (const float*)d_in[2];
    const float* b_ih   = (const float*)d_in[3];
    const float* b_hh   = (const float*)d_in[4];
    const float* W1     = (const float*)d_in[5];
    const float* b1     = (const float*)d_in[6];
    const float* W2     = (const float*)d_in[7];
    const float* b2     = (const float*)d_in[8];
    float* out = (float*)d_out;

    lstm_mlp_kernel<<<dim3(256), dim3(256), 0, stream>>>(
        inputs, W_ih, W_hh, b_ih, b_hh, W1, b1, W2, b2, out);
}